// Round 3
// baseline (4130.733 us; speedup 1.0000x reference)
//
#include <hip/hip_runtime.h>
#include <stdint.h>

#define NB 16
#define HH 128
#define WW 128
#define L (HH*WW)        // 16384
#define CIN 3
#define HID 256
#define NC 21
#define CHUNK 256
#define NCHUNKS (L/CHUNK)   // 64
#define T_PER 32            // t's per wave in k_bp
#define NPACK (L/4)         // 4096 packs of 4 timesteps

// ---------------- K1: conv -> fp32 emissions, TRANSPOSED em_T[b][c][t], LDS input tile ----------------
__global__ __launch_bounds__(256) void k_conv(
    const float* __restrict__ x, const float* __restrict__ w1,
    const float* __restrict__ b1, const float* __restrict__ w2,
    const float* __restrict__ b2, float* __restrict__ emT)
{
    __shared__ float xs[CIN*4*WW];        // 3 ic x 4 rows x 128 cols = 6144 B
    int tid = threadIdx.x;
    int g  = blockIdx.x * 256 + tid;      // 0..B*L-1
    int b  = g >> 14;
    int t0 = (blockIdx.x * 256) & (L-1);  // first t of block (multiple of 256)
    int y0 = t0 >> 7;                     // first of the block's 2 rows
    int dy = tid >> 7;                    // 0 or 1
    int xx = tid & (WW-1);
    int t  = t0 + tid;

    const float* xb = x + (size_t)b * CIN * L;
    for (int i = tid; i < CIN*4*WW; i += 256) {
        int ic  = i >> 9;                 // /512
        int rem = i & 511;
        int rr  = rem >> 7;               // 0..3
        int cc  = rem & 127;
        int row = y0 - 1 + rr;
        xs[i] = (row >= 0 && row < HH) ? xb[ic*L + (row<<7) + cc] : 0.f;
    }
    __syncthreads();

    double p[27];
    #pragma unroll
    for (int ic = 0; ic < CIN; ++ic) {
        #pragma unroll
        for (int ky = 0; ky < 3; ++ky) {
            #pragma unroll
            for (int kx = 0; kx < 3; ++kx) {
                int xc = xx + kx - 1;
                float v = (xc >= 0 && xc < WW) ? xs[ic*512 + (dy+ky)*128 + xc] : 0.f;
                p[ic*9 + ky*3 + kx] = (double)v;
            }
        }
    }

    double acc[NC];
    #pragma unroll
    for (int c = 0; c < NC; ++c) acc[c] = 0.0;

    #pragma unroll 2
    for (int oc = 0; oc < HID; ++oc) {
        double hv = 0.0;                              // conv1 accum
        #pragma unroll
        for (int j = 0; j < 27; ++j) hv += (double)w1[oc*27 + j] * p[j];
        float h32 = (float)hv;                        // round conv1 to fp32
        h32 = h32 + b1[oc];                           // fp32 elementwise bias
        h32 = fmaxf(h32, 0.f);                        // relu (fp32)
        double hd = (double)h32;
        #pragma unroll
        for (int c = 0; c < NC; ++c) acc[c] += (double)w2[c*HID + oc] * hd;
    }
    float* dstb = emT + (size_t)b * NC * L;
    #pragma unroll
    for (int c = 0; c < NC; ++c) {
        float e32 = (float)acc[c];                    // round conv2 to fp32
        dstb[(size_t)c * L + t] = e32 + b2[c];        // transposed store (coalesced in t)
    }
}

// ---------------- K2a: 3-bpermute recursion, full-VALU combine tree ----------------
// s'[n] = fl( max_p fl(s[p]+T[p][n]) + e[n] ) — bitwise equal to ref by RNE monotonicity
// (exact max over the 21 candidates; duplicated candidates are exact under max).
// Calibrated model (R11=314, R2=346, R1=421 cy/step): T ~ nDS*15 + 120 + VALU_tail.
// This version: 8 p-groups (q=lane>>3) x 8 columns (c=lane&7); 3 bpermutes gather s[3q..3q+2];
// each lane computes partials for 3 states (c, c+8, 16+c); combine across the 8 p-groups
// on the VALU pipe: v_max+DPP(row_ror:8), permlane16_swap, permlane32_swap (both-results-max
// trick, verified exact in R2). Canonical s[n] lands back at lane n with 2 cndmasks.
// Est ~230-260 cy/step.
typedef int iv2 __attribute__((ext_vector_type(2)));

__global__ __launch_bounds__(64) void k_scores(
    const float* __restrict__ emT, const float* __restrict__ start,
    const float* __restrict__ endt, const float* __restrict__ trans,
    float* __restrict__ sc, int* __restrict__ last_tag)
{
    __shared__ float fin[NC];
    int l = threadIdx.x;
    int b = blockIdx.x;
    int c = l & 7;                         // column: which states I combine for
    int q = l >> 3;                        // p-group: which s[p] I gather
    int ns = l < NC ? l : NC-1;            // canonical state of this lane (store/source)

    // my 3 gathered p's (group q covers p = 3q..3q+2, clamped: dups of 20 are exact)
    int p0 = 3*q,     p1 = 3*q + 1, p2 = 3*q + 2;
    if (p0 > 20) p0 = 20;
    if (p1 > 20) p1 = 20;
    if (p2 > 20) p2 = 20;
    int ga0 = p0*4, ga1 = p1*4, ga2 = p2*4;
    asm volatile("" : "+v"(ga0), "+v"(ga1), "+v"(ga2));

    // my 3 states
    int nA = c;                            // 0..7
    int nB = c + 8;                        // 8..15
    int nC = (c < 5) ? (16 + c) : 20;      // 16..20 (c>=5 duplicates state 20: exact)

    // 9 transition constants T[p_i][n_r]
    float tA0 = trans[p0*NC + nA], tA1 = trans[p1*NC + nA], tA2 = trans[p2*NC + nA];
    float tB0 = trans[p0*NC + nB], tB1 = trans[p1*NC + nB], tB2 = trans[p2*NC + nB];
    float tC0 = trans[p0*NC + nC], tC1 = trans[p1*NC + nC], tC2 = trans[p2*NC + nC];
    asm volatile("" : "+v"(tA0), "+v"(tA1), "+v"(tA2));
    asm volatile("" : "+v"(tB0), "+v"(tB1), "+v"(tB2));
    asm volatile("" : "+v"(tC0), "+v"(tC1), "+v"(tC2));

    // emission streams for my 3 states
    const float4* erA = (const float4*)(emT + ((size_t)b * NC + nA) * L);
    const float4* erB = (const float4*)(emT + ((size_t)b * NC + nB) * L);
    const float4* erC = (const float4*)(emT + ((size_t)b * NC + nC) * L);
    float*        scp = sc + (size_t)b * NC * L;          // 84 floats per pack

    bool isA = (l < 8);
    bool isB = (l < 16);

    float sv;   // canonical: lane n holds s[n] (n = 0..20); lanes 21..63 hold dups/garbage (never sourced)

    #define BPERM(A,V) __int_as_float(__builtin_amdgcn_ds_bpermute((A), __float_as_int(V)))
    #define ROR8MAX(W) { int _t = __builtin_amdgcn_update_dpp(__float_as_int(W), __float_as_int(W), 0x128, 0xF, 0xF, false); \
                         W = fmaxf(W, __int_as_float(_t)); }
    #define PL16MAX(W) { iv2 _r = __builtin_amdgcn_permlane16_swap(__float_as_int(W), __float_as_int(W), false, false); \
                         W = fmaxf(__int_as_float(_r[0]), __int_as_float(_r[1])); }
    #define PL32MAX(W) { iv2 _r = __builtin_amdgcn_permlane32_swap(__float_as_int(W), __float_as_int(W), false, false); \
                         W = fmaxf(__int_as_float(_r[0]), __int_as_float(_r[1])); }

    #define STEP(EA, EB, EC, OUT) { \
        float s0 = BPERM(ga0, sv); \
        float s1 = BPERM(ga1, sv); \
        float s2 = BPERM(ga2, sv); \
        float wA = fmaxf(fmaxf(s0 + tA0, s1 + tA1), s2 + tA2);   /* v_max3 */ \
        float wB = fmaxf(fmaxf(s0 + tB0, s1 + tB1), s2 + tB2);   \
        float wC = fmaxf(fmaxf(s0 + tC0, s1 + tC1), s2 + tC2);   \
        ROR8MAX(wA) ROR8MAX(wB) ROR8MAX(wC)     /* merge the 2 p-groups in my 16-row */ \
        PL16MAX(wA) PL16MAX(wB) PL16MAX(wC)     /* merge row pairs within half */ \
        PL32MAX(wA) PL32MAX(wB) PL32MAX(wC)     /* merge halves: exact max over all 8 groups */ \
        float oA = wA + (EA); \
        float oB = wB + (EB); \
        float oC = wC + (EC); \
        OUT = isA ? oA : (isB ? oB : oC);       /* canonical: lane n = s'[n] */ \
        sv = OUT; }

    float4 eA0 = erA[0], eA1 = erA[1];
    float4 eB0 = erB[0], eB1 = erB[1];
    float4 eC0 = erC[0], eC1 = erC[1];

    // ---- pack 0 (t=0 init + t=1..3) ----
    float v0 = emT[((size_t)b * NC + ns) * L] + start[ns];   // s0 = fl(em[0]+start), canonical
    sv = v0;
    {
        float4 aA = eA0, aB = eB0, aC = eC0;
        eA0 = erA[2]; eB0 = erB[2]; eC0 = erC[2];
        float a1v, a2v, a3v;
        STEP(aA.y, aB.y, aC.y, a1v)
        STEP(aA.z, aB.z, aC.z, a2v)
        STEP(aA.w, aB.w, aC.w, a3v)
        if (l < NC) *(float4*)(scp + ns*4) = make_float4(v0, a1v, a2v, a3v);
    }

    // ---- packs 1..4095 ----
    for (int k = 1; k < NPACK; ++k) {
        float4 aA = (k & 1) ? eA1 : eA0;
        float4 aB = (k & 1) ? eB1 : eB0;
        float4 aC = (k & 1) ? eC1 : eC0;
        int kp = k + 2; if (kp > NPACK-1) kp = NPACK-1;
        if (k & 1) { eA1 = erA[kp]; eB1 = erB[kp]; eC1 = erC[kp]; }
        else       { eA0 = erA[kp]; eB0 = erB[kp]; eC0 = erC[kp]; }

        float b0, b1_, b2_, b3;
        STEP(aA.x, aB.x, aC.x, b0)
        STEP(aA.y, aB.y, aC.y, b1_)
        STEP(aA.z, aB.z, aC.z, b2_)
        STEP(aA.w, aB.w, aC.w, b3)
        if (l < NC) *(float4*)(scp + k*84 + ns*4) = make_float4(b0, b1_, b2_, b3);
    }
    #undef STEP
    #undef BPERM
    #undef ROR8MAX
    #undef PL16MAX
    #undef PL32MAX

    if (l < NC) fin[ns] = sv;
    __syncthreads();
    if (l == 0) {
        float bv = fin[0] + endt[0]; int bt = 0;
        #pragma unroll
        for (int j = 1; j < NC; ++j) {
            float v = fin[j] + endt[j];
            if (v > bv) { bv = v; bt = j; }
        }
        last_tag[b] = bt;
    }
}

// ---------------- K2b: parallel backpointer recovery ----------------
// bp[t][n] = first p with fl(fl(s_{t-1}[p]+T[p][n])+e[t][n]) == s_t[n]
__global__ __launch_bounds__(256) void k_bp(
    const float* __restrict__ emT, const float* __restrict__ sc,
    const float* __restrict__ trans, uint8_t* __restrict__ bp)
{
    int wave = threadIdx.x >> 6;
    int lane = threadIdx.x & 63;
    int ne   = lane < NC ? lane : NC-1;

    int bidx  = blockIdx.x;
    int b     = bidx >> 7;                              // 128 blocks per batch
    int tbase = (bidx & 127) * (4*T_PER) + wave*T_PER;

    const float* emb = emT + (size_t)b * NC * L;
    const float* scp = sc  + (size_t)b * NC * L;
    uint8_t*     bpb = bp  + (size_t)b * L * NC;

    float tc[NC];
    #pragma unroll
    for (int pp = 0; pp < NC; ++pp) tc[pp] = trans[pp*NC + ne];

    for (int t = tbase; t < tbase + T_PER; ++t) {
        if (t == 0) continue;
        float target = scp[(t>>2)*84 + ne*4 + (t&3)];
        float e      = emb[(size_t)ne * L + t];
        const float* sp = scp + ((t-1)>>2)*84 + ((t-1)&3);
        int fi = 0;
        #pragma unroll
        for (int pp = NC-1; pp >= 0; --pp) {
            float cand = (sp[pp*4] + tc[pp]) + e;
            if (cand == target) fi = pp;
        }
        if (lane < NC) bpb[(size_t)t * NC + ne] = (uint8_t)fi;
    }
}

// ---------------- K3a: per-chunk jump tables, SEGMENTED chase (exact) ----------------
__global__ __launch_bounds__(64) void k_jump(
    const uint8_t* __restrict__ bp, uint8_t* __restrict__ J)
{
    __shared__ uint32_t lds4[CHUNK*NC/4];    // 5376 B of bp rows [cs..ce)
    __shared__ uint8_t  segJ[8*NC];          // 168 B
    int l   = threadIdx.x;
    int bid = blockIdx.x;
    int b   = bid / (NCHUNKS-1);
    int k   = bid % (NCHUNKS-1) + 1;         // chunks 1..63
    int cs  = k * CHUNK;

    const uint32_t* src = (const uint32_t*)(bp + (size_t)b * L * NC + (size_t)cs * NC);
    for (int i = l; i < CHUNK*NC/4; i += 64) lds4[i] = src[i];
    __syncthreads();
    const uint8_t* lb = (const uint8_t*)lds4;

    // 168 = 8 segs x 21 hyps; chase c -> (s=c/21, h=c%21), rows s*32+31 .. s*32
    int c0 = l, c1 = l + 63, c2 = l + 126;
    bool v2 = (c2 < 8*NC);
    int t0 = c0 % NC, t1 = c1 % NC, t2 = v2 ? (c2 % NC) : 0;
    int r0 = (c0 / NC) * 32, r1 = (c1 / NC) * 32, r2 = v2 ? (c2 / NC) * 32 : 0;
    for (int i = 31; i >= 0; --i) {          // 3 independent chains -> pipelined
        t0 = lb[(r0+i)*NC + t0];
        t1 = lb[(r1+i)*NC + t1];
        if (v2) t2 = lb[(r2+i)*NC + t2];
    }
    segJ[c0] = (uint8_t)t0;
    segJ[c1] = (uint8_t)t1;
    if (v2) segJ[c2] = (uint8_t)t2;
    __syncthreads();

    if (l < NC) {
        int tag = l;
        #pragma unroll
        for (int s = 7; s >= 0; --s) tag = segJ[s*NC + tag];
        J[((size_t)b * NCHUNKS + k) * NC + l] = (uint8_t)tag;
    }
}

// ---------------- K3b: thread chunk entries through jump tables (LDS-staged J) ----------------
__global__ __launch_bounds__(64) void k_seq(
    const uint8_t* __restrict__ J, const int* __restrict__ last_tag,
    uint8_t* __restrict__ ent)
{
    __shared__ uint32_t ldsJ4[NB*NCHUNKS*NC/4];   // 21504 B
    int l = threadIdx.x;
    const uint32_t* src = (const uint32_t*)J;
    for (int i = l; i < NB*NCHUNKS*NC/4; i += 64) ldsJ4[i] = src[i];
    __syncthreads();
    const uint8_t* lj = (const uint8_t*)ldsJ4;

    if (l < NB) {
        int b = l;
        int tag = last_tag[b];                       // tag at t = L-1
        ent[b * NCHUNKS + 63] = (uint8_t)tag;
        for (int k = NCHUNKS-1; k >= 1; --k) {
            tag = lj[((size_t)b * NCHUNKS + k) * NC + tag];
            ent[b * NCHUNKS + (k-1)] = (uint8_t)tag;
        }
    }
}

// ---------------- K3c: per-chunk output, SEGMENTED re-walk from exact seed ----------------
__global__ __launch_bounds__(64) void k_out(
    const uint8_t* __restrict__ bp, const uint8_t* __restrict__ ent,
    int* __restrict__ out)
{
    __shared__ uint32_t lds4[CHUNK*NC/4];
    __shared__ uint8_t  segJ[8*NC];
    __shared__ uint8_t  E[8];
    __shared__ int      tags[CHUNK];
    int l   = threadIdx.x;
    int bid = blockIdx.x;
    int b   = bid >> 6;
    int k   = bid & (NCHUNKS-1);
    int cs  = k * CHUNK;

    const uint32_t* src = (const uint32_t*)(bp + (size_t)b * L * NC + (size_t)cs * NC);
    for (int i = l; i < CHUNK*NC/4; i += 64) lds4[i] = src[i];
    __syncthreads();
    const uint8_t* lb = (const uint8_t*)lds4;

    // phase 2: segment tables (chunk 0 seg 0 crosses t=0: its result is never used)
    int c0 = l, c1 = l + 63, c2 = l + 126;
    bool v2 = (c2 < 8*NC);
    int t0 = c0 % NC, t1 = c1 % NC, t2 = v2 ? (c2 % NC) : 0;
    int r0 = (c0 / NC) * 32, r1 = (c1 / NC) * 32, r2 = v2 ? (c2 / NC) * 32 : 0;
    for (int i = 31; i >= 0; --i) {
        t0 = lb[(r0+i)*NC + t0];
        t1 = lb[(r1+i)*NC + t1];
        if (v2) t2 = lb[(r2+i)*NC + t2];
    }
    segJ[c0] = (uint8_t)(t0 & 31);           // mask: chunk-0/seg-0 garbage stays in-bounds
    segJ[c1] = (uint8_t)(t1 & 31);
    if (v2) segJ[c2] = (uint8_t)(t2 & 31);
    __syncthreads();

    // phase 3: compose segment entry tags E[s] = tag at position cs + 32s + 31
    if (l == 0) {
        int tag = ent[b * NCHUNKS + k];              // exact tag at ce-1
        E[7] = (uint8_t)tag;
        #pragma unroll
        for (int s = 7; s >= 1; --s) { tag = segJ[s*NC + tag]; E[s-1] = (uint8_t)tag; }
    }
    __syncthreads();

    // phase 4: 8 lanes re-walk their 32 rows
    if (l < 8) {
        int tag = E[l];
        int rb  = l * 32;
        for (int i = 31; i >= 0; --i) {              // t = cs+rb+i down to cs+rb
            tags[rb + i] = tag;
            tag = lb[(rb+i)*NC + tag];               // hop at t=0 (chunk 0) unused
        }
    }
    __syncthreads();

    int4* ob = (int4*)(out + (size_t)b * L + cs);
    ob[l] = ((const int4*)tags)[l];                  // 64 lanes x int4 = 256 ints
}

extern "C" void kernel_launch(void* const* d_in, const int* in_sizes, int n_in,
                              void* d_out, int out_size, void* d_ws, size_t ws_size,
                              hipStream_t stream) {
    const float* x  = (const float*)d_in[0];
    const float* w1 = (const float*)d_in[1];
    const float* b1 = (const float*)d_in[2];
    const float* w2 = (const float*)d_in[3];
    const float* b2 = (const float*)d_in[4];
    const float* st = (const float*)d_in[5];
    const float* en = (const float*)d_in[6];
    const float* tr = (const float*)d_in[7];
    int* out = (int*)d_out;

    char* ws = (char*)d_ws;
    float*   em = (float*)ws;                                    // em_T: 22,020,096 B
    float*   sc = (float*)(ws + (size_t)NB*L*NC*4);              // packed scores: 22,020,096 B
    uint8_t* bp = (uint8_t*)(ws + (size_t)NB*L*NC*8);            // 5,505,024 B
    int*     lt = (int*)(ws + (size_t)NB*L*NC*9);                // int[NB]
    // J/ent alias the em region: em is dead after k_bp completes (stream-ordered).
    uint8_t* J   = (uint8_t*)ws;                                 // NB*64*21 = 21,504 B
    uint8_t* ent = (uint8_t*)ws + 21504;                         // NB*64 = 1,024 B

    k_conv  <<<dim3(NB*L/256),       dim3(256), 0, stream>>>(x, w1, b1, w2, b2, em);
    k_scores<<<dim3(NB),             dim3(64),  0, stream>>>(em, st, en, tr, sc, lt);
    k_bp    <<<dim3(NB*128),         dim3(256), 0, stream>>>(em, sc, tr, bp);
    k_jump  <<<dim3(NB*(NCHUNKS-1)), dim3(64),  0, stream>>>(bp, J);
    k_seq   <<<dim3(1),              dim3(64),  0, stream>>>(J, lt, ent);
    k_out   <<<dim3(NB*NCHUNKS),     dim3(64),  0, stream>>>(bp, ent, out);
}

// Round 5
// 1994.768 us; speedup vs baseline: 2.0708x; 2.0708x over previous
//
#include <hip/hip_runtime.h>
#include <stdint.h>

#define NB 16
#define HH 128
#define WW 128
#define L (HH*WW)        // 16384
#define CIN 3
#define HID 256
#define NC 21
#define CHUNK 256
#define NCHUNKS (L/CHUNK)   // 64
#define T_PER 32            // t's per wave in k_bp
#define NPACK (L/4)         // 4096 packs of 4 timesteps

// ---------------- K1: conv -> fp32 emissions, TRANSPOSED em_T[b][c][t], LDS input tile ----------------
__global__ __launch_bounds__(256) void k_conv(
    const float* __restrict__ x, const float* __restrict__ w1,
    const float* __restrict__ b1, const float* __restrict__ w2,
    const float* __restrict__ b2, float* __restrict__ emT)
{
    __shared__ float xs[CIN*4*WW];        // 3 ic x 4 rows x 128 cols = 6144 B
    int tid = threadIdx.x;
    int g  = blockIdx.x * 256 + tid;      // 0..B*L-1
    int b  = g >> 14;
    int t0 = (blockIdx.x * 256) & (L-1);  // first t of block (multiple of 256)
    int y0 = t0 >> 7;                     // first of the block's 2 rows
    int dy = tid >> 7;                    // 0 or 1
    int xx = tid & (WW-1);
    int t  = t0 + tid;

    const float* xb = x + (size_t)b * CIN * L;
    for (int i = tid; i < CIN*4*WW; i += 256) {
        int ic  = i >> 9;                 // /512
        int rem = i & 511;
        int rr  = rem >> 7;               // 0..3
        int cc  = rem & 127;
        int row = y0 - 1 + rr;
        xs[i] = (row >= 0 && row < HH) ? xb[ic*L + (row<<7) + cc] : 0.f;
    }
    __syncthreads();

    double p[27];
    #pragma unroll
    for (int ic = 0; ic < CIN; ++ic) {
        #pragma unroll
        for (int ky = 0; ky < 3; ++ky) {
            #pragma unroll
            for (int kx = 0; kx < 3; ++kx) {
                int xc = xx + kx - 1;
                float v = (xc >= 0 && xc < WW) ? xs[ic*512 + (dy+ky)*128 + xc] : 0.f;
                p[ic*9 + ky*3 + kx] = (double)v;
            }
        }
    }

    double acc[NC];
    #pragma unroll
    for (int c = 0; c < NC; ++c) acc[c] = 0.0;

    #pragma unroll 2
    for (int oc = 0; oc < HID; ++oc) {
        double hv = 0.0;                              // conv1 accum
        #pragma unroll
        for (int j = 0; j < 27; ++j) hv += (double)w1[oc*27 + j] * p[j];
        float h32 = (float)hv;                        // round conv1 to fp32
        h32 = h32 + b1[oc];                           // fp32 elementwise bias
        h32 = fmaxf(h32, 0.f);                        // relu (fp32)
        double hd = (double)h32;
        #pragma unroll
        for (int c = 0; c < NC; ++c) acc[c] += (double)w2[c*HID + oc] * hd;
    }
    float* dstb = emT + (size_t)b * NC * L;
    #pragma unroll
    for (int c = 0; c < NC; ++c) {
        float e32 = (float)acc[c];                    // round conv2 to fp32
        dstb[(size_t)c * L + t] = e32 + b2[c];        // transposed store (coalesced in t)
    }
}

// ---------------- K2a: LDS-resident state + ds_max_f32 combine (ONE DS level, 5 DS ops/step) ----
// RESUBMIT of R4 (bench infra failed; audit found no fault path: all LDS idx < 128 floats, all
// global offsets bounded, 16B-aligned float4s, in-order same-wave DS, plain/atomic pairs
// may-alias through the l<21 lanes so buffer access order is compiler-preserved).
// s'[n] = fl( max_p fl(s[p]+T[p][n]) + e[n] ) — bitwise equal to ref by RNE monotonicity:
// per copy c: q_c = fl(max_{p in W_c} fl(s[p]+T) + e) = max_{p in W_c} fl(fl(s+T)+e);
// ds_max over the 3 copies gives the exact 21-way value. Candidate set identical to ref.
// Ledger (cy/step): R11 9-bpermute/2-level = 314; R2 11-bperm/1-level = 346; R1 readlane = 421;
// R3 3-bperm+9 cross-VALU = 551. Floor proof: bpermute family needs >= 7 gathers + 2 combines.
// This scheme: state lives in LDS ping-pong; step = {readback (b32, off-path, feeds sc store one
// step late), init NEXT=-inf (b32 write), 2x ds_read_b128 window (3 broadcast addrs,
// conflict-free), 8 add + max tree + add e (VALU), ds_max_f32 -> NEXT[n]}. The combine happens
// IN the LDS ALU -> single dependent LDS round trip per step (atomic_t -> window-read_{t+1}).
// Pads: slots 21-23 stay -inf (init) and tc[p>20] = -inf; -inf + -inf = -inf (no NaN).
// Est ~200-235 cy/step.
#define NEGINF (-__builtin_huge_valf())

__global__ __launch_bounds__(64) void k_scores(
    const float* __restrict__ emT, const float* __restrict__ start,
    const float* __restrict__ endt, const float* __restrict__ trans,
    float* __restrict__ sc, int* __restrict__ last_tag)
{
    __shared__ float smem[128];            // two 64-float ping-pong buffers
    __shared__ float fin[NC];
    int l = threadIdx.x;
    int b = blockIdx.x;
    int c = l / 21; if (c > 2) c = 2;      // copy: lanes 0-20 / 21-41 / 42-62 (63 dups (2,20))
    int n = l - c*21; if (n > 20) n = 20;  // my state
    int wb = 8*c;                          // my p-window: floats [8c .. 8c+7]

    const float4* er4 = (const float4*)(emT + ((size_t)b * NC + n) * L);
    float*        scp = sc + (size_t)b * NC * L;          // 84 floats per pack

    // 8 transition constants T[8c+i][n]; -inf for p>20 (window pad)
    float tc0, tc1, tc2, tc3, tc4, tc5, tc6, tc7;
    {
        int p0=wb, p1=wb+1, p2=wb+2, p3=wb+3, p4=wb+4, p5=wb+5, p6=wb+6, p7=wb+7;
        tc0 = trans[p0*NC + n];
        tc1 = trans[p1*NC + n];
        tc2 = trans[p2*NC + n];
        tc3 = trans[p3*NC + n];
        tc4 = trans[p4*NC + n];
        tc5 = (p5 < NC) ? trans[p5*NC + n] : NEGINF;
        tc6 = (p6 < NC) ? trans[p6*NC + n] : NEGINF;
        tc7 = (p7 < NC) ? trans[p7*NC + n] : NEGINF;
    }
    asm volatile("" : "+v"(tc0), "+v"(tc1), "+v"(tc2), "+v"(tc3));
    asm volatile("" : "+v"(tc4), "+v"(tc5), "+v"(tc6), "+v"(tc7));

    // STEP(CUR,NXT): reads buf CUR (holds s_{t-1}), maxes q into buf NXT (becomes s_t).
    // RB = readback of s_{t-1}[l] (valid for l<21), used for the lagged sc store.
    #define STEP(CUR, NXT, EV, RB) { \
        RB = smem[(CUR)*64 + l];                           /* s_{t-1}[l], off critical path */ \
        smem[(NXT)*64 + l] = NEGINF;                       /* init next buffer */ \
        float4 ra  = *(const float4*)&smem[(CUR)*64 + wb]; \
        float4 rb4 = *(const float4*)&smem[(CUR)*64 + wb + 4]; \
        float w0 = ra.x  + tc0, w1 = ra.y  + tc1, w2 = ra.z  + tc2, w3 = ra.w  + tc3; \
        float w4 = rb4.x + tc4, w5 = rb4.y + tc5, w6 = rb4.z + tc6, w7 = rb4.w + tc7; \
        float m0 = fmaxf(fmaxf(w0, w1), w2); \
        float m1 = fmaxf(fmaxf(w3, w4), w5); \
        float m2 = fmaxf(w6, w7); \
        float q  = fmaxf(fmaxf(m0, m1), m2) + (EV);        /* q_c = fl(pr_c + e[n]) */ \
        (void)__hip_atomic_fetch_max(&smem[(NXT)*64 + n], q, \
                 __ATOMIC_RELAXED, __HIP_MEMORY_SCOPE_WORKGROUP); /* ds_max_f32 */ \
    }

    float4 ebuf0 = er4[0];
    float4 ebuf1 = er4[1];

    // ---- t=0 init + pack 0 (t=1..3) ----
    float v0 = ebuf0.x + start[n];         // s0 = fl(em[0]+start), ref order
    smem[l] = (l < NC) ? v0 : NEGINF;      // buf0 = s0, slots 21..63 = -inf
    float p0 = v0, p1, p2;                 // pending quad (p3 arrives via next pack's rbA)
    {
        float4 ev = ebuf0;
        ebuf0 = er4[2];
        float rbB, rbC, rbD;
        STEP(0, 1, ev.y, rbB)              // t=1 (rbB = s0 dup, unused)
        STEP(1, 0, ev.z, rbC)              // t=2, rbC = s1
        STEP(0, 1, ev.w, rbD)              // t=3, rbD = s2
        (void)rbB;
        p1 = rbC; p2 = rbD;
    }

    // ---- packs 1..4095; pack k stores pack k-1's quad at its first step ----
    for (int k = 1; k < NPACK; ++k) {
        float4 ev = (k & 1) ? ebuf1 : ebuf0;
        int kp = k + 2; if (kp > NPACK-1) kp = NPACK-1;
        if (k & 1) ebuf1 = er4[kp]; else ebuf0 = er4[kp];

        float rbA, rbB, rbC, rbD;
        STEP(1, 0, ev.x, rbA)              // t=4k,   rbA = s_{4k-1}: completes pack k-1
        if (l < NC) *(float4*)(scp + (k-1)*84 + n*4) = make_float4(p0, p1, p2, rbA);
        STEP(0, 1, ev.y, rbB)              // rbB = s_{4k}
        STEP(1, 0, ev.z, rbC)              // rbC = s_{4k+1}
        STEP(0, 1, ev.w, rbD)              // rbD = s_{4k+2}
        p0 = rbB; p1 = rbC; p2 = rbD;
    }
    #undef STEP

    float slast = smem[64 + l];            // t=16383 is odd -> buf1 holds s_{L-1}
    if (l < NC) {
        *(float4*)(scp + (NPACK-1)*84 + n*4) = make_float4(p0, p1, p2, slast);
        fin[n] = slast;
    }
    __syncthreads();
    if (l == 0) {
        float bv = fin[0] + endt[0]; int bt = 0;
        #pragma unroll
        for (int j = 1; j < NC; ++j) {
            float v = fin[j] + endt[j];
            if (v > bv) { bv = v; bt = j; }
        }
        last_tag[b] = bt;
    }
}

// ---------------- K2b: parallel backpointer recovery ----------------
// bp[t][n] = first p with fl(fl(s_{t-1}[p]+T[p][n])+e[t][n]) == s_t[n]
__global__ __launch_bounds__(256) void k_bp(
    const float* __restrict__ emT, const float* __restrict__ sc,
    const float* __restrict__ trans, uint8_t* __restrict__ bp)
{
    int wave = threadIdx.x >> 6;
    int lane = threadIdx.x & 63;
    int ne   = lane < NC ? lane : NC-1;

    int bidx  = blockIdx.x;
    int b     = bidx >> 7;                              // 128 blocks per batch
    int tbase = (bidx & 127) * (4*T_PER) + wave*T_PER;

    const float* emb = emT + (size_t)b * NC * L;
    const float* scp = sc  + (size_t)b * NC * L;
    uint8_t*     bpb = bp  + (size_t)b * L * NC;

    float tc[NC];
    #pragma unroll
    for (int pp = 0; pp < NC; ++pp) tc[pp] = trans[pp*NC + ne];

    for (int t = tbase; t < tbase + T_PER; ++t) {
        if (t == 0) continue;
        float target = scp[(t>>2)*84 + ne*4 + (t&3)];
        float e      = emb[(size_t)ne * L + t];
        const float* sp = scp + ((t-1)>>2)*84 + ((t-1)&3);
        int fi = 0;
        #pragma unroll
        for (int pp = NC-1; pp >= 0; --pp) {
            float cand = (sp[pp*4] + tc[pp]) + e;
            if (cand == target) fi = pp;
        }
        if (lane < NC) bpb[(size_t)t * NC + ne] = (uint8_t)fi;
    }
}

// ---------------- K3a: per-chunk jump tables, SEGMENTED chase (exact) ----------------
__global__ __launch_bounds__(64) void k_jump(
    const uint8_t* __restrict__ bp, uint8_t* __restrict__ J)
{
    __shared__ uint32_t lds4[CHUNK*NC/4];    // 5376 B of bp rows [cs..ce)
    __shared__ uint8_t  segJ[8*NC];          // 168 B
    int l   = threadIdx.x;
    int bid = blockIdx.x;
    int b   = bid / (NCHUNKS-1);
    int k   = bid % (NCHUNKS-1) + 1;         // chunks 1..63
    int cs  = k * CHUNK;

    const uint32_t* src = (const uint32_t*)(bp + (size_t)b * L * NC + (size_t)cs * NC);
    for (int i = l; i < CHUNK*NC/4; i += 64) lds4[i] = src[i];
    __syncthreads();
    const uint8_t* lb = (const uint8_t*)lds4;

    // 168 = 8 segs x 21 hyps; chase c -> (s=c/21, h=c%21), rows s*32+31 .. s*32
    int c0 = l, c1 = l + 63, c2 = l + 126;
    bool v2 = (c2 < 8*NC);
    int t0 = c0 % NC, t1 = c1 % NC, t2 = v2 ? (c2 % NC) : 0;
    int r0 = (c0 / NC) * 32, r1 = (c1 / NC) * 32, r2 = v2 ? (c2 / NC) * 32 : 0;
    for (int i = 31; i >= 0; --i) {          // 3 independent chains -> pipelined
        t0 = lb[(r0+i)*NC + t0];
        t1 = lb[(r1+i)*NC + t1];
        if (v2) t2 = lb[(r2+i)*NC + t2];
    }
    segJ[c0] = (uint8_t)t0;
    segJ[c1] = (uint8_t)t1;
    if (v2) segJ[c2] = (uint8_t)t2;
    __syncthreads();

    if (l < NC) {
        int tag = l;
        #pragma unroll
        for (int s = 7; s >= 0; --s) tag = segJ[s*NC + tag];
        J[((size_t)b * NCHUNKS + k) * NC + l] = (uint8_t)tag;
    }
}

// ---------------- K3b: thread chunk entries through jump tables (LDS-staged J) ----------------
__global__ __launch_bounds__(64) void k_seq(
    const uint8_t* __restrict__ J, const int* __restrict__ last_tag,
    uint8_t* __restrict__ ent)
{
    __shared__ uint32_t ldsJ4[NB*NCHUNKS*NC/4];   // 21504 B
    int l = threadIdx.x;
    const uint32_t* src = (const uint32_t*)J;
    for (int i = l; i < NB*NCHUNKS*NC/4; i += 64) ldsJ4[i] = src[i];
    __syncthreads();
    const uint8_t* lj = (const uint8_t*)ldsJ4;

    if (l < NB) {
        int b = l;
        int tag = last_tag[b];                       // tag at t = L-1
        ent[b * NCHUNKS + 63] = (uint8_t)tag;
        for (int k = NCHUNKS-1; k >= 1; --k) {
            tag = lj[((size_t)b * NCHUNKS + k) * NC + tag];
            ent[b * NCHUNKS + (k-1)] = (uint8_t)tag;
        }
    }
}

// ---------------- K3c: per-chunk output, SEGMENTED re-walk from exact seed ----------------
__global__ __launch_bounds__(64) void k_out(
    const uint8_t* __restrict__ bp, const uint8_t* __restrict__ ent,
    int* __restrict__ out)
{
    __shared__ uint32_t lds4[CHUNK*NC/4];
    __shared__ uint8_t  segJ[8*NC];
    __shared__ uint8_t  E[8];
    __shared__ int      tags[CHUNK];
    int l   = threadIdx.x;
    int bid = blockIdx.x;
    int b   = bid >> 6;
    int k   = bid & (NCHUNKS-1);
    int cs  = k * CHUNK;

    const uint32_t* src = (const uint32_t*)(bp + (size_t)b * L * NC + (size_t)cs * NC);
    for (int i = l; i < CHUNK*NC/4; i += 64) lds4[i] = src[i];
    __syncthreads();
    const uint8_t* lb = (const uint8_t*)lds4;

    // phase 2: segment tables (chunk 0 seg 0 crosses t=0: its result is never used)
    int c0 = l, c1 = l + 63, c2 = l + 126;
    bool v2 = (c2 < 8*NC);
    int t0 = c0 % NC, t1 = c1 % NC, t2 = v2 ? (c2 % NC) : 0;
    int r0 = (c0 / NC) * 32, r1 = (c1 / NC) * 32, r2 = v2 ? (c2 / NC) * 32 : 0;
    for (int i = 31; i >= 0; --i) {
        t0 = lb[(r0+i)*NC + t0];
        t1 = lb[(r1+i)*NC + t1];
        if (v2) t2 = lb[(r2+i)*NC + t2];
    }
    segJ[c0] = (uint8_t)(t0 & 31);           // mask: chunk-0/seg-0 garbage stays in-bounds
    segJ[c1] = (uint8_t)(t1 & 31);
    if (v2) segJ[c2] = (uint8_t)(t2 & 31);
    __syncthreads();

    // phase 3: compose segment entry tags E[s] = tag at position cs + 32s + 31
    if (l == 0) {
        int tag = ent[b * NCHUNKS + k];              // exact tag at ce-1
        E[7] = (uint8_t)tag;
        #pragma unroll
        for (int s = 7; s >= 1; --s) { tag = segJ[s*NC + tag]; E[s-1] = (uint8_t)tag; }
    }
    __syncthreads();

    // phase 4: 8 lanes re-walk their 32 rows
    if (l < 8) {
        int tag = E[l];
        int rb  = l * 32;
        for (int i = 31; i >= 0; --i) {              // t = cs+rb+i down to cs+rb
            tags[rb + i] = tag;
            tag = lb[(rb+i)*NC + tag];               // hop at t=0 (chunk 0) unused
        }
    }
    __syncthreads();

    int4* ob = (int4*)(out + (size_t)b * L + cs);
    ob[l] = ((const int4*)tags)[l];                  // 64 lanes x int4 = 256 ints
}

extern "C" void kernel_launch(void* const* d_in, const int* in_sizes, int n_in,
                              void* d_out, int out_size, void* d_ws, size_t ws_size,
                              hipStream_t stream) {
    const float* x  = (const float*)d_in[0];
    const float* w1 = (const float*)d_in[1];
    const float* b1 = (const float*)d_in[2];
    const float* w2 = (const float*)d_in[3];
    const float* b2 = (const float*)d_in[4];
    const float* st = (const float*)d_in[5];
    const float* en = (const float*)d_in[6];
    const float* tr = (const float*)d_in[7];
    int* out = (int*)d_out;

    char* ws = (char*)d_ws;
    float*   em = (float*)ws;                                    // em_T: 22,020,096 B
    float*   sc = (float*)(ws + (size_t)NB*L*NC*4);              // packed scores: 22,020,096 B
    uint8_t* bp = (uint8_t*)(ws + (size_t)NB*L*NC*8);            // 5,505,024 B
    int*     lt = (int*)(ws + (size_t)NB*L*NC*9);                // int[NB]
    // J/ent alias the em region: em is dead after k_bp completes (stream-ordered).
    uint8_t* J   = (uint8_t*)ws;                                 // NB*64*21 = 21,504 B
    uint8_t* ent = (uint8_t*)ws + 21504;                         // NB*64 = 1,024 B

    k_conv  <<<dim3(NB*L/256),       dim3(256), 0, stream>>>(x, w1, b1, w2, b2, em);
    k_scores<<<dim3(NB),             dim3(64),  0, stream>>>(em, st, en, tr, sc, lt);
    k_bp    <<<dim3(NB*128),         dim3(256), 0, stream>>>(em, sc, tr, bp);
    k_jump  <<<dim3(NB*(NCHUNKS-1)), dim3(64),  0, stream>>>(bp, J);
    k_seq   <<<dim3(1),              dim3(64),  0, stream>>>(J, lt, ent);
    k_out   <<<dim3(NB*NCHUNKS),     dim3(64),  0, stream>>>(bp, ent, out);
}